// Round 1
// baseline (368.080 us; speedup 1.0000x reference)
//
#include <hip/hip_runtime.h>
#include <stdint.h>

// Spiking ConvColumn: temporal PWL-response conv + winner-takes-all.
//   input_spikes [16, 2, 64, 64, 100] fp32 (binary)
//   weight       [32, 2, 3, 3]        fp32 in [0,1]
//   output       [16, 32, 31, 31, 149] fp32 (one-hot spikes)
#define NXS 31
#define NYS 31
#define TP 149
#define TT 100
#define RSTRIDE 104         // u32/row: 101 entries + 3 spare; %4==0 keeps b128
                            // alignment
#define NROWS 54            // 2 ci * 3 ky * 9 cols (4 sites share 9 cols)
#define NSUM 8              // per-(site,half) precomputed sum rows
                            // LDS = 62*104*4 = 25.8 KB -> 6 blk/CU
#define NBLK (16 * NYS * 8) // 3968 blocks
#define FILL4 4619          // float4s per block: 3968*4619 = 18328192 exact
#define NREC (NBLK * 128)   // 492032 (site,ch) mask records in d_ws

// argmax over 32 channels; ties -> lowest ch (jnp.argmax); both halves hold
// the combined pot, shuffles with mk<=16 stay inside each half.
#define RECORD_WIN(POTV, TIDX)                                           \
    {                                                                    \
        float v_ = (POTV); int c_ = ch;                                  \
        _Pragma("unroll")                                                \
        for (int mk = 16; mk >= 1; mk >>= 1) {                           \
            float vo = __shfl_xor(v_, mk);                               \
            int co   = __shfl_xor(c_, mk);                               \
            if (vo > v_ || (vo == v_ && co < c_)) { v_ = vo; c_ = co; }  \
        }                                                                \
        if (c_ == ch) {                                                  \
            const int tt_ = (TIDX);                                      \
            const uint32_t bit_ = 1u << (tt_ & 31);                      \
            switch (tt_ >> 5) {     /* wave-uniform branch */            \
                case 0: m0 |= bit_; break;                               \
                case 1: m1 |= bit_; break;                               \
                case 2: m2 |= bit_; break;                               \
                case 3: m3 |= bit_; break;                               \
                default: m4 |= bit_; break;                              \
            }                                                            \
        }                                                                \
    }

// ---------------------------------------------------------------------------
// Kernel 1: build + sum-rows + linear-fill-issue + 2-step jump-scan.
// The zero-fill is addressed by blockIdx (pure streaming order) and issued
// AFTER the last barrier, BEFORE the scan (LDS/VALU-only) -> stores drain
// underneath the compute. No output ones written here.
// Block = 4 waves = sites x0..x0+3 sharing one table set (9 columns).
// Wave lanes: 0-31 = 32 ch x trains 0-8 (ci=0); 32-63 = same ch x 9-17.
// Table entry k = (C[k]<<16)|M[k]: C = #spikes before time k, M = sum times.
// Scan evaluates TWO timesteps per iteration: per (j, window-edge) the pair
// {entry i, entry i+1} comes back in one ds_read2_b32; step B's index is
// clamp(v+1) which is i or i+1 -> one cndmask selects. The channel-invariant
// P0 term uses precomputed per-(site,half) sum rows (9 reads -> 1 pair).
// ---------------------------------------------------------------------------
__global__ __launch_bounds__(256) void snn_scan(
    const float* __restrict__ in,
    const float* __restrict__ weight,
    float* __restrict__ out,
    uint32_t* __restrict__ ws)
{
    __shared__ uint32_t tbl[(NROWS + NSUM) * RSTRIDE];

    const int tid  = threadIdx.x;
    const int wave = tid >> 6;
    const int lane = tid & 63;
    const int half = lane >> 5;
    const int ch   = lane & 31;

    const int bi = blockIdx.x;
    const int xg = bi & 7;                // 8 x-groups of 4 (last has 3)
    const int y  = (bi >> 3) % NYS;
    const int b  = bi / (8 * NYS);
    const int x0 = xg * 4;
    const int x  = x0 + wave;             // this wave's site (x>=31 inactive)

    // per-lane response params: r(tau)=tau/16 for tau<=m=floor(16w);
    // (48w-tau)/32 for m<tau<=n=ceil(48w)-1.
    float wA[9]; int mA[9], nA[9];
    {
        const float* wrow = weight + ch * 18 + half * 9;
#pragma unroll
        for (int j = 0; j < 9; ++j) {
            float w = wrow[j];
            float a48 = 48.0f * w;
            int m = (int)floorf(16.0f * w);
            int n = (int)ceilf(a48) - 1;
            if (n < m) n = m;
            wA[j] = a48; mA[j] = m; nA[j] = n;
        }
    }

    // ---- build 54 rows; row r owned by one lane (waves split the rows).
    // Tree-form prefix: 25-step carry chain, b128 entry stores.
    {
        const int r = lane + 14 * wave;    // lanes 0..13 of each wave
        if (lane < 14 && r < NROWS) {
            const int ci = r / 27, rem = r % 27;
            const int ky = rem / 9, col = rem % 9;
            const int h = 2 * y + ky, wc = 2 * x0 + col;
            if (wc < 64) {                 // xg=7,col=8 is OOB and unused
                const float4* rowp = (const float4*)(in +
                    (size_t)(((b * 2 + ci) * 64 + h) * 64 + wc) * TT);
                uint32_t* t = tbl + r * RSTRIDE;      // entry-0, 16B aligned
                uint32_t run = 0;
#pragma unroll 5
                for (int chunk = 0; chunk < 25; ++chunk) {
                    float4 v = rowp[chunk];
                    const uint32_t u = chunk * 4;
                    uint32_t i0 = (v.x > 0.5f) ? ((1u << 16) | u)       : 0u;
                    uint32_t i1 = (v.y > 0.5f) ? ((1u << 16) | (u + 1)) : 0u;
                    uint32_t i2 = (v.z > 0.5f) ? ((1u << 16) | (u + 2)) : 0u;
                    uint32_t i3 = (v.w > 0.5f) ? ((1u << 16) | (u + 3)) : 0u;
                    uint32_t s01 = i0 + i1;
                    uint32_t e1 = run + i0;
                    uint32_t e2 = run + s01;
                    uint32_t e3 = e2 + i2;
                    *((uint4*)(t + u)) = make_uint4(run, e1, e2, e3);
                    run = e3 + i3;         // single dependent add per chunk
                }
                t[100] = run;              // total = entry 100
            }
        }
    }
    __syncthreads();

    // ---- build 8 per-(site,half) sum rows: S[t] = sum_j T_j[t]. Packed
    // sums stay carry-free (C<=900, M<=44550). b128 reads/stores, 26 lanes
    // per row, conflict-free stride-1 pattern. Entries 101..103 are garbage
    // (never selected). Inactive site 31's rows sum garbage -> never read.
    {
        const int sr = tid >> 5;           // 0..7 = wave*2 + half
        const int L  = tid & 31;
        if (L < 26) {
            const int w2 = sr >> 1, h2 = sr & 1;
            const uint32_t* bse = tbl + (h2 * 27 + 2 * w2) * RSTRIDE + 4 * L;
            uint4 acc = make_uint4(0u, 0u, 0u, 0u);
#pragma unroll
            for (int q = 0; q < 9; ++q) {
                const uint4 v = *(const uint4*)(bse + ((q / 3) * 9 + (q % 3)) * RSTRIDE);
                acc.x += v.x; acc.y += v.y; acc.z += v.z; acc.w += v.w;
            }
            *(uint4*)(tbl + (NROWS + sr) * RSTRIDE + 4 * L) = acc;
        }
    }
    __syncthreads();

    // ---- issue linear zero-fill chunk (fire-and-forget; drains under scan).
    // Placed AFTER the last barrier so no vmcnt wait lands between here and
    // the kernel end (the scan below is LDS/VALU-only).
    {
        float4* out4 = (float4*)out + (size_t)bi * FILL4;
        const float4 z4 = make_float4(0.f, 0.f, 0.f, 0.f);
        for (int i = tid; i < FILL4; i += 256)
            out4[i] = z4;
    }

    // ---- 2-step scalar jump-scan WTA ----
    uint32_t m0 = 0, m1 = 0, m2 = 0, m3 = 0, m4 = 0;   // 149-bit spike mask
    if (x < NXS) {
        const uint32_t* Tq = tbl + (half * 27 + 2 * wave) * RSTRIDE;
        const uint32_t* Sq = tbl + (NROWS + wave * 2 + half) * RSTRIDE;
        int tp = 1;                        // tp=0: empty window, no spike
        while (tp < TP) {
            const int t1 = tp - 1;
            const float ft1 = (float)t1;
            const int b0 = (tp < TT) ? tp : TT;          // uniform
            const uint32_t sl = Sq[b0];    // P0 for step A (pair read)
            const uint32_t sh = Sq[b0 + 1];
            uint32_t P1A = 0, P2A = 0, P1B = 0, P2B = 0;
            float FA = 0.0f, FB = 0.0f;    // sum_j 48w_j * dc2_j
#pragma unroll
            for (int j = 0; j < 9; ++j) {
                const int roff = ((j / 3) * 9 + (j % 3)) * RSTRIDE; // const
                const int v1 = t1 - mA[j];
                const int v2 = t1 - nA[j];
                int i1 = v1 < 0 ? 0 : (v1 > TT ? TT : v1);   // med3
                int i2 = v2 < 0 ? 0 : (v2 > TT ? TT : v2);
                const uint32_t* p = Tq + roff;
                const uint32_t lo1 = p[i1], hi1 = p[i1 + 1]; // ds_read2_b32
                const uint32_t lo2 = p[i2], hi2 = p[i2 + 1]; // ds_read2_b32
                // step B index = clamp(v+1) = i or i+1
                const uint32_t s1 = ((uint32_t)v1 < (uint32_t)TT) ? hi1 : lo1;
                const uint32_t s2 = ((uint32_t)v2 < (uint32_t)TT) ? hi2 : lo2;
                P1A += lo1; P2A += lo2;
                P1B += s1;  P2B += s2;
                FA += wA[j] * (float)(int)((lo1 - lo2) >> 16);
                FB += wA[j] * (float)(int)((s1 - s2) >> 16);
            }
            // packed sums/differences carry-free: sum C<=900, sum M<=44550.
            {
                const uint32_t D1 = sl - P1A;   // rising window totals
                const uint32_t D2 = P1A - P2A;  // falling window totals
                float pot = (ft1 * (float)(D1 >> 16) - (float)(D1 & 0xffffu)) * 0.0625f
                          + (FA - ft1 * (float)(D2 >> 16) + (float)(D2 & 0xffffu)) * 0.03125f;
                pot += __shfl_xor(pot, 32);     // combine the two train halves
                if (__ballot(pot > 5.4f)) {
                    RECORD_WIN(pot, tp);
                    tp += 48;                   // dep=47 refractory skip
                    continue;
                }
            }
            if (tp == TP - 1) break;            // step B would be t=149
            {
                const uint32_t P0B = (tp < TT) ? sh : sl;
                const float ftB = (float)tp;
                const uint32_t D1 = P0B - P1B;
                const uint32_t D2 = P1B - P2B;
                float pot = (ftB * (float)(D1 >> 16) - (float)(D1 & 0xffffu)) * 0.0625f
                          + (FB - ftB * (float)(D2 >> 16) + (float)(D2 & 0xffffu)) * 0.03125f;
                pot += __shfl_xor(pot, 32);
                if (__ballot(pot > 5.4f)) {
                    RECORD_WIN(pot, tp + 1);
                    tp += 49;                   // (tp+1) + 48
                } else {
                    tp += 2;
                }
            }
        }
    }

    // ---- write this (site,ch) mask record (24 B, records contiguous per
    // block -> 768 B per wave, coalesced). Inactive waves write zeros. ----
    if (lane < 32) {
        uint32_t* rec = ws + ((size_t)bi * 128 + wave * 32 + ch) * 6;
        rec[0] = m0; rec[1] = m1; rec[2] = m2; rec[3] = m3; rec[4] = m4;
    }
}

// ---------------------------------------------------------------------------
// Kernel 2: scatter the 1.0s. One thread per (site,ch) record; coalesced
// 24-B read, early-out if no spikes, else <=4 scattered stores.
// Kernel boundary guarantees kernel 1's zeros are visible first.
// ---------------------------------------------------------------------------
__global__ __launch_bounds__(256) void snn_scatter(
    const uint32_t* __restrict__ ws,
    float* __restrict__ out)
{
    const int r = blockIdx.x * 256 + threadIdx.x;        // 0..NREC-1
    const uint32_t* rec = ws + (size_t)r * 6;
    const uint32_t m0 = rec[0], m1 = rec[1], m2 = rec[2];
    const uint32_t m3 = rec[3], m4 = rec[4];
    if ((m0 | m1 | m2 | m3 | m4) == 0u) return;

    const int ch = r & 31;
    const int wave = (r >> 5) & 3;
    const int bi = r >> 7;
    const int xg = bi & 7;
    const int y  = (bi >> 3) % NYS;
    const int b  = bi / (8 * NYS);
    const int x  = xg * 4 + wave;                        // x<31 (else mask==0)
    const size_t base = (size_t)(((b * 32 + ch) * 961) + y * NYS + x) * TP;

    uint32_t mw[5] = { m0, m1, m2, m3, m4 };
#pragma unroll
    for (int w = 0; w < 5; ++w) {
        uint32_t mm = mw[w];
        while (mm) {                       // <=4 spikes total per (site,ch)
            const int t = __builtin_ctz(mm);
            mm &= mm - 1;
            out[base + 32 * w + t] = 1.0f;
        }
    }
}

extern "C" void kernel_launch(void* const* d_in, const int* in_sizes, int n_in,
                              void* d_out, int out_size, void* d_ws, size_t ws_size,
                              hipStream_t stream) {
    const float* in = (const float*)d_in[0];   // input_spikes
    const float* wt = (const float*)d_in[1];   // weight
    float* out = (float*)d_out;
    uint32_t* ws = (uint32_t*)d_ws;            // 492032 * 24 B = 11.8 MB

    hipLaunchKernelGGL(snn_scan, dim3(NBLK), dim3(256), 0, stream,
                       in, wt, out, ws);
    hipLaunchKernelGGL(snn_scatter, dim3(NREC / 256), dim3(256), 0, stream,
                       ws, out);
}

// Round 2
// 359.868 us; speedup vs baseline: 1.0228x; 1.0228x over previous
//
#include <hip/hip_runtime.h>
#include <stdint.h>

// Spiking ConvColumn: temporal PWL-response conv + winner-takes-all.
//   input_spikes [16, 2, 64, 64, 100] fp32 (binary)
//   weight       [32, 2, 3, 3]        fp32 in [0,1]
//   output       [16, 32, 31, 31, 149] fp32 (one-hot spikes)
#define NXS 31
#define NYS 31
#define TP 149
#define TT 100
#define RSTRIDE 104         // u32/row; %4==0 keeps b128 alignment
                            // word w = entry w-1: word0 = 0 (entry -1),
                            // words 1..101 = entries 0..100, 102/103 = dup(T[100])
#define NROWS 54            // 2 ci * 3 ky * 9 cols (4 sites share 9 cols)
#define NSUM 8              // per-(site,half) precomputed sum rows
                            // LDS = 62*104*4 = 25.8 KB -> 6 blk/CU
#define NBLK (16 * NYS * 8) // 3968 blocks
#define FILL4 4619          // float4s per block: 3968*4619 = 18328192 exact
#define NREC (NBLK * 128)   // 492032 (site,ch) mask records in d_ws

// argmax over 32 channels; ties -> lowest ch (jnp.argmax); both halves hold
// the combined pot, shuffles with mk<=16 stay inside each half.
#define RECORD_WIN(POTV, TIDX)                                           \
    {                                                                    \
        float v_ = (POTV); int c_ = ch;                                  \
        _Pragma("unroll")                                                \
        for (int mk = 16; mk >= 1; mk >>= 1) {                           \
            float vo = __shfl_xor(v_, mk);                               \
            int co   = __shfl_xor(c_, mk);                               \
            if (vo > v_ || (vo == v_ && co < c_)) { v_ = vo; c_ = co; }  \
        }                                                                \
        if (c_ == ch) {                                                  \
            const int tt_ = (TIDX);                                      \
            const uint32_t bit_ = 1u << (tt_ & 31);                      \
            switch (tt_ >> 5) {     /* wave-uniform branch */            \
                case 0: m0 |= bit_; break;                               \
                case 1: m1 |= bit_; break;                               \
                case 2: m2 |= bit_; break;                               \
                case 3: m3 |= bit_; break;                               \
                default: m4 |= bit_; break;                              \
            }                                                            \
        }                                                                \
    }

// ---------------------------------------------------------------------------
// Kernel 1: build + sum-rows + linear-fill-issue + 2-step jump-scan.
// The zero-fill is addressed by blockIdx (pure streaming order) and issued
// AFTER the last barrier, BEFORE the scan (LDS/VALU-only) -> stores drain
// underneath the compute. No output ones written here.
// Block = 4 waves = sites x0..x0+3 sharing one table set (9 columns).
// Wave lanes: 0-31 = 32 ch x trains 0-8 (ci=0); 32-63 = same ch x 9-17.
// Entry k = (C[k]<<16)|M[k]: C = #spikes before time k, M = sum of times.
// CLAMP-FREE LAYOUT: rows are shifted one word (word w = entry w-1) with a
// leading zero word and duplicated T[100] tail. A single med3_i32 clamp of
// the entry index to [-1,100] makes the pair read {word i+1, word i+2}
// return exactly {T[clamp(i)], T[clamp(i+1)]} in every region -> the 2-step
// scan needs NO post-load selects and NO separate step-B clamp.
// ---------------------------------------------------------------------------
__global__ __launch_bounds__(256) void snn_scan(
    const float* __restrict__ in,
    const float* __restrict__ weight,
    float* __restrict__ out,
    uint32_t* __restrict__ ws)
{
    __shared__ uint32_t tbl[(NROWS + NSUM) * RSTRIDE];

    const int tid  = threadIdx.x;
    const int wave = tid >> 6;
    const int lane = tid & 63;
    const int half = lane >> 5;
    const int ch   = lane & 31;

    const int bi = blockIdx.x;
    const int xg = bi & 7;                // 8 x-groups of 4 (last has 3)
    const int y  = (bi >> 3) % NYS;
    const int b  = bi / (8 * NYS);
    const int x0 = xg * 4;
    const int x  = x0 + wave;             // this wave's site (x>=31 inactive)

    // per-lane response params: r(tau)=tau/16 for tau<=m=floor(16w);
    // (48w-tau)/32 for m<tau<=n=ceil(48w)-1.
    // qm/qn: entry index for window edge = (tp-1) - m = tp + q, q = -1-m.
    float wA[9]; int qm[9], qn[9];
    {
        const float* wrow = weight + ch * 18 + half * 9;
#pragma unroll
        for (int j = 0; j < 9; ++j) {
            float w = wrow[j];
            float a48 = 48.0f * w;
            int m = (int)floorf(16.0f * w);
            int n = (int)ceilf(a48) - 1;
            if (n < m) n = m;
            wA[j] = a48; qm[j] = -1 - m; qn[j] = -1 - n;
        }
    }

    // ---- build 54 rows; row r owned by one lane (waves split the rows).
    // Shifted layout: chunk c stores words 4c..4c+3 = P[4c-1..4c+2] where
    // P[k] = packed prefix over spikes at times < k. Carry A=P[4c-1], B=P[4c].
    {
        const int r = lane + 14 * wave;    // lanes 0..13 of each wave
        if (lane < 14 && r < NROWS) {
            const int ci = r / 27, rem = r % 27;
            const int ky = rem / 9, col = rem % 9;
            const int h = 2 * y + ky, wc = 2 * x0 + col;
            if (wc < 64) {                 // xg=7,col=8 is OOB and unused
                const float4* rowp = (const float4*)(in +
                    (size_t)(((b * 2 + ci) * 64 + h) * 64 + wc) * TT);
                uint32_t* t = tbl + r * RSTRIDE;      // word 0, 16B aligned
                uint32_t A = 0, B = 0;
#pragma unroll 5
                for (int chunk = 0; chunk < 25; ++chunk) {
                    float4 v = rowp[chunk];
                    const uint32_t u = chunk * 4;
                    uint32_t i0 = (v.x > 0.5f) ? ((1u << 16) | u)       : 0u;
                    uint32_t i1 = (v.y > 0.5f) ? ((1u << 16) | (u + 1)) : 0u;
                    uint32_t i2 = (v.z > 0.5f) ? ((1u << 16) | (u + 2)) : 0u;
                    uint32_t i3 = (v.w > 0.5f) ? ((1u << 16) | (u + 3)) : 0u;
                    uint32_t s01 = i0 + i1;
                    *((uint4*)(t + u)) = make_uint4(A, B, B + i0, B + s01);
                    A = B + s01 + i2;      // P[4c+3]
                    B = A + i3;            // P[4c+4]
                }
                // words 100..103 = {P[99], P[100], dup, dup}
                *((uint4*)(t + 100)) = make_uint4(A, B, B, B);
            }
        }
    }
    __syncthreads();

    // ---- build 8 per-(site,half) sum rows: word-wise sum of the 9 rows.
    // Packed sums stay carry-free (C<=900, M<=44550). Zero word stays zero,
    // dup words stay dup-of-sum. Inactive site 31's rows sum garbage ->
    // never read.
    {
        const int sr = tid >> 5;           // 0..7 = wave*2 + half
        const int L  = tid & 31;
        if (L < 26) {
            const int w2 = sr >> 1, h2 = sr & 1;
            const uint32_t* bse = tbl + (h2 * 27 + 2 * w2) * RSTRIDE + 4 * L;
            uint4 acc = make_uint4(0u, 0u, 0u, 0u);
#pragma unroll
            for (int q = 0; q < 9; ++q) {
                const uint4 v = *(const uint4*)(bse + ((q / 3) * 9 + (q % 3)) * RSTRIDE);
                acc.x += v.x; acc.y += v.y; acc.z += v.z; acc.w += v.w;
            }
            *(uint4*)(tbl + (NROWS + sr) * RSTRIDE + 4 * L) = acc;
        }
    }
    __syncthreads();

    // ---- issue linear zero-fill chunk (fire-and-forget; drains under scan).
    // Placed AFTER the last barrier so no vmcnt wait lands between here and
    // the kernel end (the scan below is LDS/VALU-only).
    {
        float4* out4 = (float4*)out + (size_t)bi * FILL4;
        const float4 z4 = make_float4(0.f, 0.f, 0.f, 0.f);
        for (int i = tid; i < FILL4; i += 256)
            out4[i] = z4;
    }

    // ---- 2-step scalar jump-scan WTA (clamp-free inner loop) ----
    uint32_t m0 = 0, m1 = 0, m2 = 0, m3 = 0, m4 = 0;   // 149-bit spike mask
    if (x < NXS) {
        // entry-0 pointers (word 1 of each row)
        const uint32_t* Tq = tbl + (half * 27 + 2 * wave) * RSTRIDE + 1;
        const uint32_t* Sq = tbl + (NROWS + wave * 2 + half) * RSTRIDE + 1;
        const uint32_t* Trow[9];
#pragma unroll
        for (int j = 0; j < 9; ++j)
            Trow[j] = Tq + ((j / 3) * 9 + (j % 3)) * RSTRIDE;

        int tp = 1;                        // tp=0: empty window, no spike
        while (tp < TP) {
            const float ft1 = (float)(tp - 1);
            // P0: S[min(tp,100)] / S[min(tp+1,100)] via pair read (dup tail)
            const int is = tp > TT ? TT : tp;          // wave-uniform
            const uint32_t* ps = Sq + is;
            const uint32_t sl = ps[0], sh = ps[1];     // ds_read2_b32
            uint32_t P1A = 0, P2A = 0, P1B = 0, P2B = 0;
            float FA = 0.0f, FB = 0.0f;    // sum_j 48w_j * dc2_j
#pragma unroll
            for (int j = 0; j < 9; ++j) {
                int i1 = tp + qm[j];                   // (tp-1) - m_j
                i1 = i1 > TT ? TT : i1; i1 = i1 < -1 ? -1 : i1;   // med3
                int i2 = tp + qn[j];                   // (tp-1) - n_j
                i2 = i2 > TT ? TT : i2; i2 = i2 < -1 ? -1 : i2;   // med3
                const uint32_t* p1 = Trow[j] + i1;
                const uint32_t* p2 = Trow[j] + i2;
                const uint32_t lo1 = p1[0], hi1 = p1[1];  // ds_read2_b32
                const uint32_t lo2 = p2[0], hi2 = p2[1];  // ds_read2_b32
                P1A += lo1; P2A += lo2;                // step A edge sums
                P1B += hi1; P2B += hi2;                // step B edge sums
                FA += wA[j] * (float)((lo1 - lo2) >> 16);
                FB += wA[j] * (float)((hi1 - hi2) >> 16);
            }
            // packed sums/differences carry-free: sum C<=900, sum M<=44550.
            {
                const uint32_t D1 = sl - P1A;   // rising window totals
                const uint32_t D2 = P1A - P2A;  // falling window totals
                float pot = (ft1 * (float)(D1 >> 16) - (float)(D1 & 0xffffu)) * 0.0625f
                          + (FA - ft1 * (float)(D2 >> 16) + (float)(D2 & 0xffffu)) * 0.03125f;
                pot += __shfl_xor(pot, 32);     // combine the two train halves
                if (__ballot(pot > 5.4f)) {
                    RECORD_WIN(pot, tp);
                    tp += 48;                   // dep=47 refractory skip
                    continue;
                }
            }
            if (tp == TP - 1) break;            // step B would be t=149
            {
                const float ftB = (float)tp;
                const uint32_t D1 = sh - P1B;   // P0B = sh always (dup tail)
                const uint32_t D2 = P1B - P2B;
                float pot = (ftB * (float)(D1 >> 16) - (float)(D1 & 0xffffu)) * 0.0625f
                          + (FB - ftB * (float)(D2 >> 16) + (float)(D2 & 0xffffu)) * 0.03125f;
                pot += __shfl_xor(pot, 32);
                if (__ballot(pot > 5.4f)) {
                    RECORD_WIN(pot, tp + 1);
                    tp += 49;                   // (tp+1) + 48
                } else {
                    tp += 2;
                }
            }
        }
    }

    // ---- write this (site,ch) mask record (24 B, records contiguous per
    // block -> 768 B per wave, coalesced). Inactive waves write zeros. ----
    if (lane < 32) {
        uint32_t* rec = ws + ((size_t)bi * 128 + wave * 32 + ch) * 6;
        rec[0] = m0; rec[1] = m1; rec[2] = m2; rec[3] = m3; rec[4] = m4;
    }
}

// ---------------------------------------------------------------------------
// Kernel 2: scatter the 1.0s. One thread per (site,ch) record; coalesced
// 24-B read, early-out if no spikes, else <=4 scattered stores.
// Kernel boundary guarantees kernel 1's zeros are visible first.
// ---------------------------------------------------------------------------
__global__ __launch_bounds__(256) void snn_scatter(
    const uint32_t* __restrict__ ws,
    float* __restrict__ out)
{
    const int r = blockIdx.x * 256 + threadIdx.x;        // 0..NREC-1
    const uint32_t* rec = ws + (size_t)r * 6;
    const uint32_t m0 = rec[0], m1 = rec[1], m2 = rec[2];
    const uint32_t m3 = rec[3], m4 = rec[4];
    if ((m0 | m1 | m2 | m3 | m4) == 0u) return;

    const int ch = r & 31;
    const int wave = (r >> 5) & 3;
    const int bi = r >> 7;
    const int xg = bi & 7;
    const int y  = (bi >> 3) % NYS;
    const int b  = bi / (8 * NYS);
    const int x  = xg * 4 + wave;                        // x<31 (else mask==0)
    const size_t base = (size_t)(((b * 32 + ch) * 961) + y * NYS + x) * TP;

    uint32_t mw[5] = { m0, m1, m2, m3, m4 };
#pragma unroll
    for (int w = 0; w < 5; ++w) {
        uint32_t mm = mw[w];
        while (mm) {                       // <=4 spikes total per (site,ch)
            const int t = __builtin_ctz(mm);
            mm &= mm - 1;
            out[base + 32 * w + t] = 1.0f;
        }
    }
}

extern "C" void kernel_launch(void* const* d_in, const int* in_sizes, int n_in,
                              void* d_out, int out_size, void* d_ws, size_t ws_size,
                              hipStream_t stream) {
    const float* in = (const float*)d_in[0];   // input_spikes
    const float* wt = (const float*)d_in[1];   // weight
    float* out = (float*)d_out;
    uint32_t* ws = (uint32_t*)d_ws;            // 492032 * 24 B = 11.8 MB

    hipLaunchKernelGGL(snn_scan, dim3(NBLK), dim3(256), 0, stream,
                       in, wt, out, ws);
    hipLaunchKernelGGL(snn_scatter, dim3(NREC / 256), dim3(256), 0, stream,
                       ws, out);
}